// Round 1
// baseline (1106.887 us; speedup 1.0000x reference)
//
#include <hip/hip_runtime.h>

// PaiNN update, fused single kernel, bf16 MFMA (16x16x32), fp32 accumulate.
// N=200000 nodes, F=128. Tile = 32 nodes per 256-thread block (4 waves).
// Wave w owns feature columns [32w, 32w+32) in ALL GEMMs so per-(node,f)
// state (Uv[c], inner, a_*) stays in registers across the whole pipeline.

#define NT 32
#define STRA 136   // smA row stride in bf16 (128 + 8 pad)
#define STRM 264   // smM (mlp_in) row stride (256 + 8 pad)
#define STRH 136   // smH row stride (128 + 8 pad)

typedef __attribute__((ext_vector_type(8))) short bf16x8;
typedef __attribute__((ext_vector_type(4))) short short4v;
typedef __attribute__((ext_vector_type(4))) float f32x4;

#define MFMA16(a, b, c) __builtin_amdgcn_mfma_f32_16x16x32_bf16(a, b, c, 0, 0, 0)

__device__ __forceinline__ short f2bf(float x) {
    union { float f; unsigned u; } v; v.f = x;
    unsigned r = v.u + 0x7fffu + ((v.u >> 16) & 1u);   // round-to-nearest-even
    return (short)(r >> 16);
}

// Transpose + fp32->bf16 all weights into ws (K-contiguous per output column):
//   Ut  [g=0..127][k=0..127]  at ws + 0
//   Vt  [g=0..127][k=0..127]  at ws + 16384
//   M1t [g=0..127][k=0..255]  at ws + 32768
//   M2t [g=0..383][k=0..127]  at ws + 65536      (total 114688 shorts = 224 KB)
__global__ void prep_weights(const float* __restrict__ Uw, const float* __restrict__ Vw,
                             const float* __restrict__ m1w, const float* __restrict__ m2w,
                             short* __restrict__ ws) {
    int idx = blockIdx.x * 256 + threadIdx.x;
    if (idx < 16384) {
        int g = idx >> 7, k = idx & 127;
        ws[idx]         = f2bf(Uw[k * 128 + g]);
        ws[16384 + idx] = f2bf(Vw[k * 128 + g]);
    } else if (idx < 49152) {
        int j = idx - 16384;           // m1_w is (256,128): out[g][k] = in[k][g]
        int g = j >> 8, k = j & 255;
        ws[32768 + j] = f2bf(m1w[k * 128 + g]);
    } else if (idx < 98304) {
        int j = idx - 49152;           // m2_w is (128,384): out[g][k] = in[k][g]
        int g = j >> 7, k = j & 127;
        ws[65536 + j] = f2bf(m2w[k * 384 + g]);
    }
}

__global__ __launch_bounds__(256, 2)
void painn_fused(const float* __restrict__ nf,
                 const float* __restrict__ Ub, const float* __restrict__ Vb,
                 const float* __restrict__ m1b, const float* __restrict__ m2b,
                 const short* __restrict__ wbuf,
                 float* __restrict__ out) {
    extern __shared__ short lds[];
    short* smA = lds;                 // [96][STRA]  rows r = c*32 + node_local (bf16)
    short* smM = smA + 96 * STRA;     // [32][STRM]  mlp_in: cols 0..127 = Vv_norm, 128..255 = scalar
    short* smH = smM + 32 * STRM;     // [32][STRH]  h (post-silu)

    const short* Ut  = wbuf;
    const short* Vt  = wbuf + 16384;
    const short* M1t = wbuf + 32768;
    const short* M2t = wbuf + 65536;

    const int tid  = threadIdx.x;
    const int wave = tid >> 6;
    const int lane = tid & 63;
    const int fc   = lane & 15;       // MFMA col within 16-tile (C/D: col = lane&15)
    const int quad = lane >> 4;       // C/D: row = quad*4 + reg ; A/B: k = quad*8 + j
    const int ntg0 = wave * 2;        // this wave's first global N-tile (of 16 cols)
    const long nodebase = (long)blockIdx.x * NT;

    // ---------------- stage node_feat tile -> LDS (bf16) ----------------
    {
        const float* src = nf + nodebase * 512;
        #pragma unroll
        for (int it = 0; it < 16; ++it) {
            int chunk = tid + 256 * it;            // 32 rows * 128 float4-chunks
            int n = chunk >> 7;
            int col = (chunk & 127) << 2;
            const float4 v = *(const float4*)(src + n * 512 + col);
            short4v s;
            s.x = f2bf(v.x); s.y = f2bf(v.y); s.z = f2bf(v.z); s.w = f2bf(v.w);
            if (col < 128) {                       // scalar part -> mlp_in right half
                *(short4v*)&smM[n * STRM + 128 + col] = s;
            } else {                               // vector part -> A tile, rows c*32+n
                int vc = col - 128;
                int c = vc >> 7, k = vc & 127;
                *(short4v*)&smA[(c * 32 + n) * STRA + k] = s;
            }
        }
    }
    __syncthreads();

    // ---------------- GEMM1: Uv, Vv = nv @ {U_w, V_w} ----------------
    // M = 96 (3 c-blocks x 32 nodes), K = 128, Ncols: this wave's 32.
    f32x4 accU[2][3][2], accV[2][3][2];   // [nt][c][mt]
    #pragma unroll
    for (int nt = 0; nt < 2; ++nt)
        #pragma unroll
        for (int c = 0; c < 3; ++c)
            #pragma unroll
            for (int s = 0; s < 2; ++s) { accU[nt][c][s] = (f32x4)(0.0f); accV[nt][c][s] = (f32x4)(0.0f); }

    #pragma unroll
    for (int kb = 0; kb < 4; ++kb) {
        const int koff = kb * 32 + quad * 8;
        bf16x8 af[3][2];
        #pragma unroll
        for (int c = 0; c < 3; ++c)
            #pragma unroll
            for (int s = 0; s < 2; ++s)
                af[c][s] = *(const bf16x8*)&smA[(c * 32 + s * 16 + fc) * STRA + koff];
        bf16x8 bu[2], bv[2];
        #pragma unroll
        for (int nt = 0; nt < 2; ++nt) {
            const int g = (ntg0 + nt) * 16 + fc;
            bu[nt] = *(const bf16x8*)&Ut[g * 128 + koff];
            bv[nt] = *(const bf16x8*)&Vt[g * 128 + koff];
        }
        #pragma unroll
        for (int nt = 0; nt < 2; ++nt)
            #pragma unroll
            for (int c = 0; c < 3; ++c)
                #pragma unroll
                for (int s = 0; s < 2; ++s) {
                    accU[nt][c][s] = MFMA16(af[c][s], bu[nt], accU[nt][c][s]);
                    accV[nt][c][s] = MFMA16(af[c][s], bv[nt], accV[nt][c][s]);
                }
    }

    // ---- epilogue 1: +bias, inner = sum_c Uv*Vv, norm -> mlp_in left half
    float inner[2][2][4];
    #pragma unroll
    for (int nt = 0; nt < 2; ++nt) {
        const int g = (ntg0 + nt) * 16 + fc;
        const float ub = Ub[g], vb = Vb[g];
        #pragma unroll
        for (int s = 0; s < 2; ++s)
            #pragma unroll
            for (int i = 0; i < 4; ++i) {
                float u0 = accU[nt][0][s][i] + ub;
                float u1 = accU[nt][1][s][i] + ub;
                float u2 = accU[nt][2][s][i] + ub;
                float v0 = accV[nt][0][s][i] + vb;
                float v1 = accV[nt][1][s][i] + vb;
                float v2 = accV[nt][2][s][i] + vb;
                accU[nt][0][s][i] = u0; accU[nt][1][s][i] = u1; accU[nt][2][s][i] = u2;
                inner[nt][s][i] = u0 * v0 + u1 * v1 + u2 * v2;
                const float nrm = sqrtf(v0 * v0 + v1 * v1 + v2 * v2);
                const int nl = s * 16 + quad * 4 + i;
                smM[nl * STRM + g] = f2bf(nrm);
            }
    }
    __syncthreads();

    // ---------------- GEMM2: h = silu(mlp_in @ m1_w + b) ----------------
    f32x4 acc2[2][2];                    // [nt][mt]
    #pragma unroll
    for (int nt = 0; nt < 2; ++nt) { acc2[nt][0] = (f32x4)(0.0f); acc2[nt][1] = (f32x4)(0.0f); }
    #pragma unroll
    for (int kb = 0; kb < 8; ++kb) {
        const int koff = kb * 32 + quad * 8;
        bf16x8 a0 = *(const bf16x8*)&smM[fc * STRM + koff];
        bf16x8 a1 = *(const bf16x8*)&smM[(16 + fc) * STRM + koff];
        #pragma unroll
        for (int nt = 0; nt < 2; ++nt) {
            const int g = (ntg0 + nt) * 16 + fc;
            bf16x8 b = *(const bf16x8*)&M1t[g * 256 + koff];
            acc2[nt][0] = MFMA16(a0, b, acc2[nt][0]);
            acc2[nt][1] = MFMA16(a1, b, acc2[nt][1]);
        }
    }
    #pragma unroll
    for (int nt = 0; nt < 2; ++nt) {
        const int g = (ntg0 + nt) * 16 + fc;
        const float bb = m1b[g];
        #pragma unroll
        for (int mt = 0; mt < 2; ++mt)
            #pragma unroll
            for (int i = 0; i < 4; ++i) {
                const float x = acc2[nt][mt][i] + bb;
                const float sl = x / (1.0f + __expf(-x));
                const int nl = mt * 16 + quad * 4 + i;
                smH[nl * STRH + g] = f2bf(sl);
            }
    }
    __syncthreads();

    // ---------------- GEMM3: mlp_out = h @ m2_w ----------------
    // Wave w takes N-tiles {2w,2w+1} of each of a_vv (cols 0..127),
    // a_sv (128..255), a_ss (256..383) -> same (node,f) pairs as GEMM1.
    f32x4 acc3[3][2][2];                 // [part][nt][mt]
    #pragma unroll
    for (int p = 0; p < 3; ++p)
        #pragma unroll
        for (int nt = 0; nt < 2; ++nt) { acc3[p][nt][0] = (f32x4)(0.0f); acc3[p][nt][1] = (f32x4)(0.0f); }
    #pragma unroll
    for (int kb = 0; kb < 4; ++kb) {
        const int koff = kb * 32 + quad * 8;
        bf16x8 a0 = *(const bf16x8*)&smH[fc * STRH + koff];
        bf16x8 a1 = *(const bf16x8*)&smH[(16 + fc) * STRH + koff];
        #pragma unroll
        for (int p = 0; p < 3; ++p)
            #pragma unroll
            for (int nt = 0; nt < 2; ++nt) {
                const int gcol = p * 128 + (ntg0 + nt) * 16 + fc;
                bf16x8 b = *(const bf16x8*)&M2t[gcol * 128 + koff];
                acc3[p][nt][0] = MFMA16(a0, b, acc3[p][nt][0]);
                acc3[p][nt][1] = MFMA16(a1, b, acc3[p][nt][1]);
            }
    }

    // ---------------- epilogue: residual add, write out ----------------
    #pragma unroll
    for (int nt = 0; nt < 2; ++nt) {
        const int g = (ntg0 + nt) * 16 + fc;
        const float bvv = m2b[g], bsv = m2b[128 + g], bss = m2b[256 + g];
        #pragma unroll
        for (int mt = 0; mt < 2; ++mt)
            #pragma unroll
            for (int i = 0; i < 4; ++i) {
                const int nl = mt * 16 + quad * 4 + i;
                const long base = (nodebase + nl) * 512;
                const float avv = acc3[0][nt][mt][i] + bvv;
                const float asv = acc3[1][nt][mt][i] + bsv;
                const float ass = acc3[2][nt][mt][i] + bss;
                const float ds  = asv * inner[nt][mt][i] + ass;
                out[base + g] = nf[base + g] + ds;
                #pragma unroll
                for (int c = 0; c < 3; ++c) {
                    const float dv = avv * accU[nt][c][mt][i];
                    out[base + 128 + c * 128 + g] = nf[base + 128 + c * 128 + g] + dv;
                }
            }
    }
}

extern "C" void kernel_launch(void* const* d_in, const int* in_sizes, int n_in,
                              void* d_out, int out_size, void* d_ws, size_t ws_size,
                              hipStream_t stream) {
    (void)in_sizes; (void)n_in; (void)out_size; (void)ws_size;
    const float* node_feat = (const float*)d_in[0];
    const float* U_w  = (const float*)d_in[1];
    const float* U_b  = (const float*)d_in[2];
    const float* V_w  = (const float*)d_in[3];
    const float* V_b  = (const float*)d_in[4];
    const float* m1_w = (const float*)d_in[5];
    const float* m1_b = (const float*)d_in[6];
    const float* m2_w = (const float*)d_in[7];
    const float* m2_b = (const float*)d_in[8];
    short* wbuf = (short*)d_ws;          // needs 224 KB of workspace

    prep_weights<<<384, 256, 0, stream>>>(U_w, V_w, m1_w, m2_w, wbuf);

    const int nblocks = 200000 / NT;     // 6250, exact
    const size_t lds_bytes = (size_t)(96 * STRA + 32 * STRM + 32 * STRH) * sizeof(short); // 51712
    painn_fused<<<nblocks, 256, lds_bytes, stream>>>(
        node_feat, U_b, V_b, m1_b, m2_b, wbuf, (float*)d_out);
}

// Round 2
// 936.484 us; speedup vs baseline: 1.1820x; 1.1820x over previous
//
#include <hip/hip_runtime.h>

// PaiNN update, fused single kernel, bf16 MFMA (16x16x32), fp32 accumulate.
// Round 2: NT=16 nodes/block (was 32), LDS 25.5 KB -> up to 6 blocks/CU
// (was 2). Staging + epilogue loads batched to avoid serialized latency.
// Wave w owns feature columns [32w, 32w+32) in ALL GEMMs so per-(node,f)
// state (Uv[c], inner, a_*) stays in registers across the whole pipeline.

#define NT 16
#define STRA 136   // smA row stride in bf16 (128 + 8 pad)
#define STRS 136   // smS (scalar half of mlp_in)
#define STRN 136   // smN (Vv_norm half of mlp_in)
#define STRH 136   // smH (post-silu h)

typedef __attribute__((ext_vector_type(8))) short bf16x8;
typedef __attribute__((ext_vector_type(4))) short short4v;
typedef __attribute__((ext_vector_type(4))) float f32x4;

#define MFMA16(a, b, c) __builtin_amdgcn_mfma_f32_16x16x32_bf16(a, b, c, 0, 0, 0)

__device__ __forceinline__ short f2bf(float x) {
    union { float f; unsigned u; } v; v.f = x;
    unsigned r = v.u + 0x7fffu + ((v.u >> 16) & 1u);   // round-to-nearest-even
    return (short)(r >> 16);
}

// Transpose + fp32->bf16 all weights into ws (K-contiguous per output column):
//   Ut  [g=0..127][k=0..127]  at ws + 0
//   Vt  [g=0..127][k=0..127]  at ws + 16384
//   M1t [g=0..127][k=0..255]  at ws + 32768
//   M2t [g=0..383][k=0..127]  at ws + 65536      (total 114688 shorts = 224 KB)
__global__ void prep_weights(const float* __restrict__ Uw, const float* __restrict__ Vw,
                             const float* __restrict__ m1w, const float* __restrict__ m2w,
                             short* __restrict__ ws) {
    int idx = blockIdx.x * 256 + threadIdx.x;
    if (idx < 16384) {
        int g = idx >> 7, k = idx & 127;
        ws[idx]         = f2bf(Uw[k * 128 + g]);
        ws[16384 + idx] = f2bf(Vw[k * 128 + g]);
    } else if (idx < 49152) {
        int j = idx - 16384;           // m1_w is (256,128): out[g][k] = in[k][g]
        int g = j >> 8, k = j & 255;
        ws[32768 + j] = f2bf(m1w[k * 128 + g]);
    } else if (idx < 98304) {
        int j = idx - 49152;           // m2_w is (128,384): out[g][k] = in[k][g]
        int g = j >> 7, k = j & 127;
        ws[65536 + j] = f2bf(m2w[k * 384 + g]);
    }
}

__global__ __launch_bounds__(256, 4)
void painn_fused(const float* __restrict__ nf,
                 const float* __restrict__ Ub, const float* __restrict__ Vb,
                 const float* __restrict__ m1b, const float* __restrict__ m2b,
                 const short* __restrict__ wbuf,
                 float* __restrict__ out) {
    extern __shared__ short lds[];
    short* smA = lds;                 // [48][STRA]  rows r = c*16 + node_local
    short* smS = smA + 48 * STRA;     // [16][STRS]  scalar half of mlp_in
    short* smN = smS + 16 * STRS;     // [16][STRN]  Vv_norm half of mlp_in
    short* smH = smN + 16 * STRN;     // [16][STRH]  h (post-silu)

    const short* Ut  = wbuf;
    const short* Vt  = wbuf + 16384;
    const short* M1t = wbuf + 32768;
    const short* M2t = wbuf + 65536;

    const int tid  = threadIdx.x;
    const int wave = tid >> 6;
    const int lane = tid & 63;
    const int fc   = lane & 15;       // MFMA col within 16-tile (C/D: col = lane&15)
    const int quad = lane >> 4;       // C/D: row = quad*4 + reg ; A/B: k = quad*8 + j
    const int ntg0 = wave * 2;        // this wave's first global N-tile (of 16 cols)
    const long nodebase = (long)blockIdx.x * NT;

    // ---------------- stage node_feat tile -> LDS (bf16) ----------------
    {
        const float* src = nf + nodebase * 512;
        float4 v[8];
        #pragma unroll
        for (int it = 0; it < 8; ++it) {
            int chunk = tid + 256 * it;            // 16 rows * 128 float4-chunks
            int n = chunk >> 7;
            int col = (chunk & 127) << 2;
            v[it] = *(const float4*)(src + n * 512 + col);
        }
        #pragma unroll
        for (int it = 0; it < 8; ++it) {
            int chunk = tid + 256 * it;
            int n = chunk >> 7;
            int col = (chunk & 127) << 2;
            short4v s;
            s.x = f2bf(v[it].x); s.y = f2bf(v[it].y);
            s.z = f2bf(v[it].z); s.w = f2bf(v[it].w);
            if (col < 128) {                       // scalar part
                *(short4v*)&smS[n * STRS + col] = s;
            } else {                               // vector part, rows c*16+n
                int vc = col - 128;
                int c = vc >> 7, k = vc & 127;
                *(short4v*)&smA[(c * 16 + n) * STRA + k] = s;
            }
        }
    }
    __syncthreads();

    // ---------------- GEMM1: Uv, Vv = nv @ {U_w, V_w} ----------------
    // M = 48 (3 c-blocks x 16 nodes), K = 128, Ncols: this wave's 32.
    f32x4 accU[2][3], accV[2][3];
    #pragma unroll
    for (int nt = 0; nt < 2; ++nt)
        #pragma unroll
        for (int c = 0; c < 3; ++c) { accU[nt][c] = (f32x4)(0.0f); accV[nt][c] = (f32x4)(0.0f); }

    #pragma unroll
    for (int kb = 0; kb < 4; ++kb) {
        const int koff = kb * 32 + quad * 8;
        bf16x8 af[3];
        #pragma unroll
        for (int c = 0; c < 3; ++c)
            af[c] = *(const bf16x8*)&smA[(c * 16 + fc) * STRA + koff];
        bf16x8 bu[2], bv[2];
        #pragma unroll
        for (int nt = 0; nt < 2; ++nt) {
            const int g = (ntg0 + nt) * 16 + fc;
            bu[nt] = *(const bf16x8*)&Ut[g * 128 + koff];
            bv[nt] = *(const bf16x8*)&Vt[g * 128 + koff];
        }
        #pragma unroll
        for (int nt = 0; nt < 2; ++nt)
            #pragma unroll
            for (int c = 0; c < 3; ++c) {
                accU[nt][c] = MFMA16(af[c], bu[nt], accU[nt][c]);
                accV[nt][c] = MFMA16(af[c], bv[nt], accV[nt][c]);
            }
    }

    // ---- epilogue 1: +bias, inner = sum_c Uv*Vv, norm -> smN
    float inner[2][4];
    #pragma unroll
    for (int nt = 0; nt < 2; ++nt) {
        const int g = (ntg0 + nt) * 16 + fc;
        const float ub = Ub[g], vb = Vb[g];
        #pragma unroll
        for (int i = 0; i < 4; ++i) {
            float u0 = accU[nt][0][i] + ub;
            float u1 = accU[nt][1][i] + ub;
            float u2 = accU[nt][2][i] + ub;
            float v0 = accV[nt][0][i] + vb;
            float v1 = accV[nt][1][i] + vb;
            float v2 = accV[nt][2][i] + vb;
            accU[nt][0][i] = u0; accU[nt][1][i] = u1; accU[nt][2][i] = u2;
            inner[nt][i] = u0 * v0 + u1 * v1 + u2 * v2;
            const float nrm = sqrtf(v0 * v0 + v1 * v1 + v2 * v2);
            const int nl = quad * 4 + i;
            smN[nl * STRN + g] = f2bf(nrm);
        }
    }
    __syncthreads();

    // ---------------- GEMM2: h = silu(mlp_in @ m1_w + b) ----------------
    // mlp_in = [ norm (k=0..127, smN) | scalar (k=128..255, smS) ]
    f32x4 acc2[2];
    acc2[0] = (f32x4)(0.0f); acc2[1] = (f32x4)(0.0f);
    #pragma unroll
    for (int kb = 0; kb < 8; ++kb) {
        const int kk = (kb & 3) * 32 + quad * 8;
        bf16x8 a0 = (kb < 4) ? *(const bf16x8*)&smN[fc * STRN + kk]
                             : *(const bf16x8*)&smS[fc * STRS + kk];
        #pragma unroll
        for (int nt = 0; nt < 2; ++nt) {
            const int g = (ntg0 + nt) * 16 + fc;
            bf16x8 b = *(const bf16x8*)&M1t[g * 256 + kb * 32 + quad * 8];
            acc2[nt] = MFMA16(a0, b, acc2[nt]);
        }
    }
    #pragma unroll
    for (int nt = 0; nt < 2; ++nt) {
        const int g = (ntg0 + nt) * 16 + fc;
        const float bb = m1b[g];
        #pragma unroll
        for (int i = 0; i < 4; ++i) {
            const float x = acc2[nt][i] + bb;
            const float sl = x / (1.0f + __expf(-x));
            const int nl = quad * 4 + i;
            smH[nl * STRH + g] = f2bf(sl);
        }
    }
    __syncthreads();

    // ---------------- GEMM3: mlp_out = h @ m2_w ----------------
    f32x4 acc3[3][2];
    #pragma unroll
    for (int p = 0; p < 3; ++p) { acc3[p][0] = (f32x4)(0.0f); acc3[p][1] = (f32x4)(0.0f); }
    #pragma unroll
    for (int kb = 0; kb < 4; ++kb) {
        const int koff = kb * 32 + quad * 8;
        bf16x8 a0 = *(const bf16x8*)&smH[fc * STRH + koff];
        #pragma unroll
        for (int p = 0; p < 3; ++p)
            #pragma unroll
            for (int nt = 0; nt < 2; ++nt) {
                const int gcol = p * 128 + (ntg0 + nt) * 16 + fc;
                bf16x8 b = *(const bf16x8*)&M2t[gcol * 128 + koff];
                acc3[p][nt] = MFMA16(a0, b, acc3[p][nt]);
            }
    }

    // ---------------- epilogue: residual add, write out ----------------
    #pragma unroll
    for (int nt = 0; nt < 2; ++nt) {
        const int g = (ntg0 + nt) * 16 + fc;
        const float bvv = m2b[g], bsv = m2b[128 + g], bss = m2b[256 + g];
        float nfv[4][4];
        #pragma unroll
        for (int i = 0; i < 4; ++i) {      // batch the re-reads
            const long base = (nodebase + quad * 4 + i) * 512;
            nfv[i][0] = nf[base + g];
            nfv[i][1] = nf[base + 128 + g];
            nfv[i][2] = nf[base + 256 + g];
            nfv[i][3] = nf[base + 384 + g];
        }
        #pragma unroll
        for (int i = 0; i < 4; ++i) {
            const long base = (nodebase + quad * 4 + i) * 512;
            const float avv = acc3[0][nt][i] + bvv;
            const float asv = acc3[1][nt][i] + bsv;
            const float ass = acc3[2][nt][i] + bss;
            const float ds  = asv * inner[nt][i] + ass;
            out[base + g] = nfv[i][0] + ds;
            #pragma unroll
            for (int c = 0; c < 3; ++c)
                out[base + 128 + c * 128 + g] = nfv[i][c + 1] + avv * accU[nt][c][i];
        }
    }
}

extern "C" void kernel_launch(void* const* d_in, const int* in_sizes, int n_in,
                              void* d_out, int out_size, void* d_ws, size_t ws_size,
                              hipStream_t stream) {
    (void)in_sizes; (void)n_in; (void)out_size; (void)ws_size;
    const float* node_feat = (const float*)d_in[0];
    const float* U_w  = (const float*)d_in[1];
    const float* U_b  = (const float*)d_in[2];
    const float* V_w  = (const float*)d_in[3];
    const float* V_b  = (const float*)d_in[4];
    const float* m1_w = (const float*)d_in[5];
    const float* m1_b = (const float*)d_in[6];
    const float* m2_w = (const float*)d_in[7];
    const float* m2_b = (const float*)d_in[8];
    short* wbuf = (short*)d_ws;          // needs 224 KB of workspace

    prep_weights<<<384, 256, 0, stream>>>(U_w, V_w, m1_w, m2_w, wbuf);

    const int nblocks = 200000 / NT;     // 12500, exact
    const size_t lds_bytes = (size_t)(48 * STRA + 16 * STRS + 16 * STRN + 16 * STRH) * sizeof(short); // 26112
    painn_fused<<<nblocks, 256, lds_bytes, stream>>>(
        node_feat, U_b, V_b, m1_b, m2_b, wbuf, (float*)d_out);
}